// Round 8
// baseline (1616.263 us; speedup 1.0000x reference)
//
#include <hip/hip_runtime.h>
#include <hip/hip_bf16.h>

// GCN: N=50000, E=800000, hidden 64, 5 convs (relu on first 4).
// f32 tensors, int32 edge_index, f32 d_out[N].  ws_size in [19.8, 26.0) MB.
// Round-7: 351 us. k_scatter ~53 us (random 4B writes -> 52.8 MB full-line writebacks);
// k_gconv 52 us: per-node serial gather loop is the floor (~3 serialized memory rounds
// per node). This round: tile-parallel gconv — block per 64-node tile, y[64][64] f32 in
// LDS, edges streamed edge-parallel (coalesced packed-record loads, gather + ds_add_f32,
// no dependent chains), then bias/relu + 64x64 matmul with W-column in VGPRs and
// wave-uniform ds_read_b128 broadcasts of the activation row.
// bucket entries packed: src | (dst&63)<<16  (valid because N < 65536).
// Workspace (~17.0 MB): gA bf16[N*64] | gB bf16[N*64] | bucket u32[E] | row_start i32[N+1]
//                       | cursor i32[N] | cnt i32[N] | dinv f32[N] | zg f32[N] | bsum i32[257]

#define TPB 256
#define TILE 64
typedef __hip_bfloat16 bf16;
#define B2F __bfloat162float

__global__ void k_zero_cnt(int* __restrict__ cnt, int n) {
    int i = blockIdx.x * blockDim.x + threadIdx.x;
    if (i < n) cnt[i] = 0;
}

__global__ void k_hist(const int* __restrict__ dst, int* __restrict__ cnt, int E, int n) {
    int e = blockIdx.x * blockDim.x + threadIdx.x;
    if (e < E) {
        int d = dst[e];
        if ((unsigned)d < (unsigned)n) atomicAdd(&cnt[d], 1);
    }
}

__global__ void k_blocksum(const int* __restrict__ cnt, int* __restrict__ bsum, int n) {
    __shared__ int s[TPB];
    int i = blockIdx.x * TPB + threadIdx.x;
    s[threadIdx.x] = (i < n) ? cnt[i] : 0;
    __syncthreads();
    for (int off = TPB / 2; off > 0; off >>= 1) {
        if (threadIdx.x < off) s[threadIdx.x] += s[threadIdx.x + off];
        __syncthreads();
    }
    if (threadIdx.x == 0) bsum[blockIdx.x] = s[0];
}

__global__ void k_scan_bsum(int* __restrict__ bsum, int nb) {
    __shared__ int s[TPB];
    int t = threadIdx.x;
    int v = (t < nb) ? bsum[t] : 0;
    s[t] = v;
    __syncthreads();
    for (int off = 1; off < TPB; off <<= 1) {
        int u = (t >= off) ? s[t - off] : 0;
        __syncthreads();
        s[t] += u;
        __syncthreads();
    }
    if (t < nb) bsum[t] = s[t] - v;  // exclusive
}

__global__ void k_scan_final(const int* __restrict__ cnt, const int* __restrict__ bsum,
                             int* __restrict__ row_start, int* __restrict__ cursor,
                             float* __restrict__ dinv, int n) {
    __shared__ int s[TPB];
    int t = threadIdx.x;
    int i = blockIdx.x * TPB + t;
    int v = (i < n) ? cnt[i] : 0;
    s[t] = v;
    __syncthreads();
    for (int off = 1; off < TPB; off <<= 1) {
        int u = (t >= off) ? s[t - off] : 0;
        __syncthreads();
        s[t] += u;
        __syncthreads();
    }
    if (i < n) {
        int excl = bsum[blockIdx.x] + s[t] - v;
        row_start[i] = excl;
        cursor[i] = excl;
        dinv[i] = rsqrtf((float)v + 1.0f);   // +1 self-loop
        if (i == n - 1) row_start[n] = excl + v;
    }
}

// bucket entry: src | (dst & 63) << 16   (N < 65536)
__global__ void k_scatter(const int* __restrict__ src, const int* __restrict__ dst,
                          int* __restrict__ cursor, unsigned* __restrict__ bucket,
                          int E, int n) {
    int e = blockIdx.x * blockDim.x + threadIdx.x;
    if (e < E) {
        int d = dst[e], s = src[e];
        if ((unsigned)d >= (unsigned)n || (unsigned)s >= (unsigned)n) return;
        int pos = atomicAdd(&cursor[d], 1);
        if ((unsigned)pos < (unsigned)E)
            bucket[pos] = (unsigned)s | ((unsigned)(d & (TILE - 1)) << 16);  // replay-safe
    }
}

// g1[i][j] = (sum_{k<4} x[i][k] * W_in[k][j]) * dinv[i]   (premultiplied)
__global__ void k_mm_in(const float* __restrict__ x, const float* __restrict__ W,
                        const float* __restrict__ dinv, bf16* __restrict__ g, int n) {
    int t = blockIdx.x * blockDim.x + threadIdx.x;
    if (t >= n * 64) return;
    int i = t >> 6, j = t & 63;
    float acc = 0.f;
#pragma unroll
    for (int k = 0; k < 4; ++k) acc = fmaf(x[i * 4 + k], W[k * 64 + j], acc);
    g[t] = __float2bfloat16(acc * dinv[i]);
}

// Streams the tile's edge range into the LDS y-tile via gather + ds_add_f32.
__device__ __forceinline__ void tile_edges(float* __restrict__ sY,
                                           const bf16* __restrict__ gIn,
                                           const unsigned* __restrict__ bucket,
                                           int e0, int e1, int wave, int lane,
                                           unsigned nm1, unsigned Em1) {
    for (int base = e0 + wave * 64; base < e1; base += 4 * 64) {
        int cnt = min(64, e1 - base);
        unsigned rec = bucket[min((unsigned)(base + lane), Em1)];  // coalesced
        int k = 0;
        for (; k + 8 <= cnt; k += 8) {
            unsigned r0 = (unsigned)__builtin_amdgcn_readlane(rec, k + 0);
            unsigned r1 = (unsigned)__builtin_amdgcn_readlane(rec, k + 1);
            unsigned r2 = (unsigned)__builtin_amdgcn_readlane(rec, k + 2);
            unsigned r3 = (unsigned)__builtin_amdgcn_readlane(rec, k + 3);
            unsigned r4 = (unsigned)__builtin_amdgcn_readlane(rec, k + 4);
            unsigned r5 = (unsigned)__builtin_amdgcn_readlane(rec, k + 5);
            unsigned r6 = (unsigned)__builtin_amdgcn_readlane(rec, k + 6);
            unsigned r7 = (unsigned)__builtin_amdgcn_readlane(rec, k + 7);
            float v0 = B2F(gIn[(size_t)min(r0 & 0xFFFFu, nm1) * 64 + lane]);
            float v1 = B2F(gIn[(size_t)min(r1 & 0xFFFFu, nm1) * 64 + lane]);
            float v2 = B2F(gIn[(size_t)min(r2 & 0xFFFFu, nm1) * 64 + lane]);
            float v3 = B2F(gIn[(size_t)min(r3 & 0xFFFFu, nm1) * 64 + lane]);
            float v4 = B2F(gIn[(size_t)min(r4 & 0xFFFFu, nm1) * 64 + lane]);
            float v5 = B2F(gIn[(size_t)min(r5 & 0xFFFFu, nm1) * 64 + lane]);
            float v6 = B2F(gIn[(size_t)min(r6 & 0xFFFFu, nm1) * 64 + lane]);
            float v7 = B2F(gIn[(size_t)min(r7 & 0xFFFFu, nm1) * 64 + lane]);
            atomicAdd(&sY[((r0 >> 16) & 63) * 64 + lane], v0);
            atomicAdd(&sY[((r1 >> 16) & 63) * 64 + lane], v1);
            atomicAdd(&sY[((r2 >> 16) & 63) * 64 + lane], v2);
            atomicAdd(&sY[((r3 >> 16) & 63) * 64 + lane], v3);
            atomicAdd(&sY[((r4 >> 16) & 63) * 64 + lane], v4);
            atomicAdd(&sY[((r5 >> 16) & 63) * 64 + lane], v5);
            atomicAdd(&sY[((r6 >> 16) & 63) * 64 + lane], v6);
            atomicAdd(&sY[((r7 >> 16) & 63) * 64 + lane], v7);
        }
        for (; k < cnt; ++k) {
            unsigned r = (unsigned)__builtin_amdgcn_readlane(rec, k);
            float v = B2F(gIn[(size_t)min(r & 0xFFFFu, nm1) * 64 + lane]);
            atomicAdd(&sY[((r >> 16) & 63) * 64 + lane], v);
        }
    }
}

// Tiled fused layer: block = 64-node tile. y-tile in LDS; edge-parallel aggregation;
// a = relu(dd*y + bias); gOut = (a @ W) * dd with W-column in VGPRs,
// activation rows read as wave-uniform ds_read_b128 broadcasts.
__global__ __launch_bounds__(TPB) void k_gconv_t(
    const bf16* __restrict__ gIn, const float* __restrict__ dinv,
    const int* __restrict__ row_start, const unsigned* __restrict__ bucket,
    const float* __restrict__ bias, const float* __restrict__ W,
    bf16* __restrict__ gOut, int n, int E) {
    __shared__ float sY[TILE * 64];
    __shared__ float sDD[TILE];
    int tid = threadIdx.x, wave = tid >> 6, lane = tid & 63;
    int t0 = blockIdx.x * TILE;

    // init y with self term (g premultiplied) + per-row dinv
    for (int r = wave; r < TILE; r += 4) {
        int d = t0 + r;
        float v = 0.f;
        if (d < n) v = B2F(gIn[(size_t)d * 64 + lane]);
        sY[r * 64 + lane] = v;
        if (lane == 0) sDD[r] = (d < n) ? dinv[d] : 0.f;
    }
    int e0 = row_start[t0];
    int e1 = row_start[min(t0 + TILE, n)];
    e0 = max(0, min(e0, E)); e1 = max(e0, min(e1, E));
    __syncthreads();

    tile_edges(sY, gIn, bucket, e0, e1, wave, lane, (unsigned)(n - 1), (unsigned)(E - 1));
    __syncthreads();

    // transform: a = relu(dd*y + bias)
    float bj = bias[lane];
    for (int r = wave; r < TILE; r += 4)
        sY[r * 64 + lane] = fmaxf(fmaf(sDD[r], sY[r * 64 + lane], bj), 0.f);
    __syncthreads();

    // matmul: W column j in registers, reused over this wave's 16 rows
    float wcol[64];
#pragma unroll
    for (int k = 0; k < 64; ++k) wcol[k] = W[k * 64 + lane];
    for (int r = wave; r < TILE; r += 4) {
        int d = t0 + r;
        if (d >= n) break;                       // wave-uniform
        const float4* ap = (const float4*)&sY[r * 64];
        float acc = 0.f;
#pragma unroll
        for (int k4 = 0; k4 < 16; ++k4) {
            float4 a4 = ap[k4];                  // uniform address -> broadcast b128
            acc = fmaf(a4.x, wcol[4 * k4 + 0], acc);
            acc = fmaf(a4.y, wcol[4 * k4 + 1], acc);
            acc = fmaf(a4.z, wcol[4 * k4 + 2], acc);
            acc = fmaf(a4.w, wcol[4 * k4 + 3], acc);
        }
        gOut[(size_t)d * 64 + lane] = __float2bfloat16(acc * sDD[r]);
    }
}

// Tiled last hidden conv fused with 64->1 matmul: zg[d] = (relu(dd*y+b) . Wout) * dd
__global__ __launch_bounds__(TPB) void k_gconv_z_t(
    const bf16* __restrict__ gIn, const float* __restrict__ dinv,
    const int* __restrict__ row_start, const unsigned* __restrict__ bucket,
    const float* __restrict__ bias, const float* __restrict__ Wout,
    float* __restrict__ zg, int n, int E) {
    __shared__ float sY[TILE * 64];
    __shared__ float sDD[TILE];
    int tid = threadIdx.x, wave = tid >> 6, lane = tid & 63;
    int t0 = blockIdx.x * TILE;
    for (int r = wave; r < TILE; r += 4) {
        int d = t0 + r;
        float v = 0.f;
        if (d < n) v = B2F(gIn[(size_t)d * 64 + lane]);
        sY[r * 64 + lane] = v;
        if (lane == 0) sDD[r] = (d < n) ? dinv[d] : 0.f;
    }
    int e0 = row_start[t0];
    int e1 = row_start[min(t0 + TILE, n)];
    e0 = max(0, min(e0, E)); e1 = max(e0, min(e1, E));
    __syncthreads();
    tile_edges(sY, gIn, bucket, e0, e1, wave, lane, (unsigned)(n - 1), (unsigned)(E - 1));
    __syncthreads();
    float bj = bias[lane], wj = Wout[lane];
    for (int r = wave; r < TILE; r += 4) {
        int d = t0 + r;
        if (d >= n) break;
        float v = fmaxf(fmaf(sDD[r], sY[r * 64 + lane], bj), 0.f) * wj;
#pragma unroll
        for (int off = 32; off > 0; off >>= 1) v += __shfl_down(v, off);
        if (lane == 0) zg[d] = v * sDD[r];
    }
}

// out[d] = dd*(zg[d] + sum zg[s]) + b_out.  One wave per node, lane = neighbor.
__global__ __launch_bounds__(TPB) void k_out(
    const float* __restrict__ zg, const float* __restrict__ dinv,
    const int* __restrict__ row_start, const unsigned* __restrict__ bucket,
    const float* __restrict__ b_out, float* __restrict__ out, int n, int E) {
    int t = blockIdx.x * blockDim.x + threadIdx.x;
    int d = t >> 6, lane = t & 63;
    if (d >= n) return;
    int k0 = row_start[d], k1 = row_start[d + 1];
    k1 = min(k1, E); k0 = max(min(k0, k1), 0);
    unsigned nm1 = (unsigned)(n - 1);
    float v = 0.f;
    for (int k = k0 + lane; k < k1; k += 64) {
        unsigned s = min(bucket[k] & 0xFFFFu, nm1);
        v += zg[s];
    }
#pragma unroll
    for (int off = 32; off > 0; off >>= 1) v += __shfl_down(v, off);
    if (lane == 0) out[d] = fmaf(zg[d] + v, dinv[d], b_out[0]);
}

extern "C" void kernel_launch(void* const* d_in, const int* in_sizes, int n_in,
                              void* d_out, int out_size, void* d_ws, size_t ws_size,
                              hipStream_t stream) {
    const float* x     = (const float*)d_in[0];
    const int*   ei    = (const int*)d_in[1];
    const float* W_in  = (const float*)d_in[2];
    const float* b_in  = (const float*)d_in[3];
    const float* W_h   = (const float*)d_in[4];
    const float* b_h   = (const float*)d_in[5];
    const float* W_out = (const float*)d_in[6];
    const float* b_out = (const float*)d_in[7];
    float* out = (float*)d_out;

    int N = in_sizes[0] / 4;
    int E = in_sizes[1] / 2;
    const int* src = ei;
    const int* dst = ei + E;

    char* ws = (char*)d_ws;
    bf16* gA           = (bf16*)ws;     ws += (size_t)N * 64 * 2;
    bf16* gB           = (bf16*)ws;     ws += (size_t)N * 64 * 2;
    unsigned* bucket   = (unsigned*)ws; ws += (size_t)E * 4;
    int*  row_start    = (int*)ws;      ws += (size_t)(N + 1) * 4;
    int*  cursor       = (int*)ws;      ws += (size_t)N * 4;
    int*  cnt          = (int*)ws;      ws += (size_t)N * 4;
    float* dinv        = (float*)ws;    ws += (size_t)N * 4;
    float* zg          = (float*)ws;    ws += (size_t)N * 4;
    int*  bsum         = (int*)ws;      // 257 ints

    int gN  = (N + TPB - 1) / TPB;       // scan chunk count (<=256 for N<=65536)
    int gE  = (E + TPB - 1) / TPB;
    int gNF = (N * 64 + TPB - 1) / TPB;
    int gN4 = (N + 3) / 4;               // 4 nodes/block (k_out)
    int gT  = (N + TILE - 1) / TILE;     // tiles

    // ---- CSR build + norms ----
    k_zero_cnt<<<gN, TPB, 0, stream>>>(cnt, N);
    k_hist<<<gE, TPB, 0, stream>>>(dst, cnt, E, N);
    k_blocksum<<<gN, TPB, 0, stream>>>(cnt, bsum, N);
    k_scan_bsum<<<1, TPB, 0, stream>>>(bsum, gN);
    k_scan_final<<<gN, TPB, 0, stream>>>(cnt, bsum, row_start, cursor, dinv, N);
    k_scatter<<<gE, TPB, 0, stream>>>(src, dst, cursor, bucket, E, N);

    // ---- layers (feature buffers premultiplied by dinv) ----
    k_mm_in<<<gNF, TPB, 0, stream>>>(x, W_in, dinv, gA, N);
    k_gconv_t<<<gT, TPB, 0, stream>>>(gA, dinv, row_start, bucket, b_in, W_h, gB, N, E);
    k_gconv_t<<<gT, TPB, 0, stream>>>(gB, dinv, row_start, bucket, b_h, W_h + 4096, gA, N, E);
    k_gconv_t<<<gT, TPB, 0, stream>>>(gA, dinv, row_start, bucket, b_h + 64, W_h + 8192, gB, N, E);
    k_gconv_z_t<<<gT, TPB, 0, stream>>>(gB, dinv, row_start, bucket, b_h + 128, W_out, zg, N, E);
    k_out<<<gN4, TPB, 0, stream>>>(zg, dinv, row_start, bucket, b_out, out, N, E);
}

// Round 9
// 1425.523 us; speedup vs baseline: 1.1338x; 1.1338x over previous
//
#include <hip/hip_runtime.h>
#include <hip/hip_bf16.h>

// GCN: N=50000, E=800000, hidden 64, 5 convs (relu on first 4).
// f32 tensors, int32 edge_index, f32 d_out[N].  ws_size in [19.8, 26.0) MB.
// Round-8 post-mortem: tiled edge-parallel gconv was correct but wave-starved
// (782 blocks x 4 waves, occupancy 26%, VALUBusy 4% -> 365 us/layer).
// This round: same structure, TILE 64->32 (1563 blocks) and 512-thread blocks
// (8 waves) -> up to 32 waves/CU; per-wave edge count drops 256->~64.
// bucket entry: src | (dst & 31) << 16   (src < 65536 since N = 50000).
// Workspace (~17.0 MB): gA bf16[N*64] | gB bf16[N*64] | bucket u32[E] | row_start i32[N+1]
//                       | cursor i32[N] | cnt i32[N] | dinv f32[N] | zg f32[N] | bsum i32[257]

#define TPB 256
#define TPB_T 512          // tiled kernels: 8 waves/block
#define NWAVES 8
#define TILE 32
typedef __hip_bfloat16 bf16;
#define B2F __bfloat162float

__global__ void k_zero_cnt(int* __restrict__ cnt, int n) {
    int i = blockIdx.x * blockDim.x + threadIdx.x;
    if (i < n) cnt[i] = 0;
}

__global__ void k_hist(const int* __restrict__ dst, int* __restrict__ cnt, int E, int n) {
    int e = blockIdx.x * blockDim.x + threadIdx.x;
    if (e < E) {
        int d = dst[e];
        if ((unsigned)d < (unsigned)n) atomicAdd(&cnt[d], 1);
    }
}

__global__ void k_blocksum(const int* __restrict__ cnt, int* __restrict__ bsum, int n) {
    __shared__ int s[TPB];
    int i = blockIdx.x * TPB + threadIdx.x;
    s[threadIdx.x] = (i < n) ? cnt[i] : 0;
    __syncthreads();
    for (int off = TPB / 2; off > 0; off >>= 1) {
        if (threadIdx.x < off) s[threadIdx.x] += s[threadIdx.x + off];
        __syncthreads();
    }
    if (threadIdx.x == 0) bsum[blockIdx.x] = s[0];
}

__global__ void k_scan_bsum(int* __restrict__ bsum, int nb) {
    __shared__ int s[TPB];
    int t = threadIdx.x;
    int v = (t < nb) ? bsum[t] : 0;
    s[t] = v;
    __syncthreads();
    for (int off = 1; off < TPB; off <<= 1) {
        int u = (t >= off) ? s[t - off] : 0;
        __syncthreads();
        s[t] += u;
        __syncthreads();
    }
    if (t < nb) bsum[t] = s[t] - v;  // exclusive
}

__global__ void k_scan_final(const int* __restrict__ cnt, const int* __restrict__ bsum,
                             int* __restrict__ row_start, int* __restrict__ cursor,
                             float* __restrict__ dinv, int n) {
    __shared__ int s[TPB];
    int t = threadIdx.x;
    int i = blockIdx.x * TPB + t;
    int v = (i < n) ? cnt[i] : 0;
    s[t] = v;
    __syncthreads();
    for (int off = 1; off < TPB; off <<= 1) {
        int u = (t >= off) ? s[t - off] : 0;
        __syncthreads();
        s[t] += u;
        __syncthreads();
    }
    if (i < n) {
        int excl = bsum[blockIdx.x] + s[t] - v;
        row_start[i] = excl;
        cursor[i] = excl;
        dinv[i] = rsqrtf((float)v + 1.0f);   // +1 self-loop
        if (i == n - 1) row_start[n] = excl + v;
    }
}

// bucket entry: src | (dst & (TILE-1)) << 16
__global__ void k_scatter(const int* __restrict__ src, const int* __restrict__ dst,
                          int* __restrict__ cursor, unsigned* __restrict__ bucket,
                          int E, int n) {
    int e = blockIdx.x * blockDim.x + threadIdx.x;
    if (e < E) {
        int d = dst[e], s = src[e];
        if ((unsigned)d >= (unsigned)n || (unsigned)s >= (unsigned)n) return;
        int pos = atomicAdd(&cursor[d], 1);
        if ((unsigned)pos < (unsigned)E)
            bucket[pos] = (unsigned)s | ((unsigned)(d & (TILE - 1)) << 16);  // replay-safe
    }
}

// g1[i][j] = (sum_{k<4} x[i][k] * W_in[k][j]) * dinv[i]   (premultiplied)
__global__ void k_mm_in(const float* __restrict__ x, const float* __restrict__ W,
                        const float* __restrict__ dinv, bf16* __restrict__ g, int n) {
    int t = blockIdx.x * blockDim.x + threadIdx.x;
    if (t >= n * 64) return;
    int i = t >> 6, j = t & 63;
    float acc = 0.f;
#pragma unroll
    for (int k = 0; k < 4; ++k) acc = fmaf(x[i * 4 + k], W[k * 64 + j], acc);
    g[t] = __float2bfloat16(acc * dinv[i]);
}

// Streams the tile's edge range into the LDS y-tile via gather + ds_add_f32.
// Edge-parallel: no dependent accumulation chains; 8 loads in flight per wave.
__device__ __forceinline__ void tile_edges(float* __restrict__ sY,
                                           const bf16* __restrict__ gIn,
                                           const unsigned* __restrict__ bucket,
                                           int e0, int e1, int wave, int lane,
                                           unsigned nm1, unsigned Em1) {
    for (int base = e0 + wave * 64; base < e1; base += NWAVES * 64) {
        int cnt = min(64, e1 - base);
        unsigned rec = bucket[min((unsigned)(base + lane), Em1)];  // coalesced
        int k = 0;
        for (; k + 8 <= cnt; k += 8) {
            unsigned r0 = (unsigned)__builtin_amdgcn_readlane(rec, k + 0);
            unsigned r1 = (unsigned)__builtin_amdgcn_readlane(rec, k + 1);
            unsigned r2 = (unsigned)__builtin_amdgcn_readlane(rec, k + 2);
            unsigned r3 = (unsigned)__builtin_amdgcn_readlane(rec, k + 3);
            unsigned r4 = (unsigned)__builtin_amdgcn_readlane(rec, k + 4);
            unsigned r5 = (unsigned)__builtin_amdgcn_readlane(rec, k + 5);
            unsigned r6 = (unsigned)__builtin_amdgcn_readlane(rec, k + 6);
            unsigned r7 = (unsigned)__builtin_amdgcn_readlane(rec, k + 7);
            float v0 = B2F(gIn[(size_t)min(r0 & 0xFFFFu, nm1) * 64 + lane]);
            float v1 = B2F(gIn[(size_t)min(r1 & 0xFFFFu, nm1) * 64 + lane]);
            float v2 = B2F(gIn[(size_t)min(r2 & 0xFFFFu, nm1) * 64 + lane]);
            float v3 = B2F(gIn[(size_t)min(r3 & 0xFFFFu, nm1) * 64 + lane]);
            float v4 = B2F(gIn[(size_t)min(r4 & 0xFFFFu, nm1) * 64 + lane]);
            float v5 = B2F(gIn[(size_t)min(r5 & 0xFFFFu, nm1) * 64 + lane]);
            float v6 = B2F(gIn[(size_t)min(r6 & 0xFFFFu, nm1) * 64 + lane]);
            float v7 = B2F(gIn[(size_t)min(r7 & 0xFFFFu, nm1) * 64 + lane]);
            atomicAdd(&sY[((r0 >> 16) & (TILE - 1)) * 64 + lane], v0);
            atomicAdd(&sY[((r1 >> 16) & (TILE - 1)) * 64 + lane], v1);
            atomicAdd(&sY[((r2 >> 16) & (TILE - 1)) * 64 + lane], v2);
            atomicAdd(&sY[((r3 >> 16) & (TILE - 1)) * 64 + lane], v3);
            atomicAdd(&sY[((r4 >> 16) & (TILE - 1)) * 64 + lane], v4);
            atomicAdd(&sY[((r5 >> 16) & (TILE - 1)) * 64 + lane], v5);
            atomicAdd(&sY[((r6 >> 16) & (TILE - 1)) * 64 + lane], v6);
            atomicAdd(&sY[((r7 >> 16) & (TILE - 1)) * 64 + lane], v7);
        }
        for (; k < cnt; ++k) {
            unsigned r = (unsigned)__builtin_amdgcn_readlane(rec, k);
            float v = B2F(gIn[(size_t)min(r & 0xFFFFu, nm1) * 64 + lane]);
            atomicAdd(&sY[((r >> 16) & (TILE - 1)) * 64 + lane], v);
        }
    }
}

// Tiled fused layer: block = 32-node tile, 8 waves. y-tile in LDS; edge-parallel
// aggregation; a = relu(dd*y + bias); gOut = (a @ W) * dd.
__global__ __launch_bounds__(TPB_T) void k_gconv_t(
    const bf16* __restrict__ gIn, const float* __restrict__ dinv,
    const int* __restrict__ row_start, const unsigned* __restrict__ bucket,
    const float* __restrict__ bias, const float* __restrict__ W,
    bf16* __restrict__ gOut, int n, int E) {
    __shared__ float sY[TILE * 64];
    __shared__ float sDD[TILE];
    int tid = threadIdx.x, wave = tid >> 6, lane = tid & 63;
    int t0 = blockIdx.x * TILE;

    // init y with self term (g premultiplied) + per-row dinv
    for (int r = wave; r < TILE; r += NWAVES) {
        int d = t0 + r;
        float v = 0.f;
        if (d < n) v = B2F(gIn[(size_t)d * 64 + lane]);
        sY[r * 64 + lane] = v;
        if (lane == 0) sDD[r] = (d < n) ? dinv[d] : 0.f;
    }
    int e0 = row_start[t0];
    int e1 = row_start[min(t0 + TILE, n)];
    e0 = max(0, min(e0, E)); e1 = max(e0, min(e1, E));
    __syncthreads();

    tile_edges(sY, gIn, bucket, e0, e1, wave, lane, (unsigned)(n - 1), (unsigned)(E - 1));
    __syncthreads();

    // transform: a = relu(dd*y + bias)
    float bj = bias[lane];
    for (int r = wave; r < TILE; r += NWAVES)
        sY[r * 64 + lane] = fmaxf(fmaf(sDD[r], sY[r * 64 + lane], bj), 0.f);
    __syncthreads();

    // matmul: W column `lane` reused over this wave's rows
    float wcol[64];
#pragma unroll
    for (int k = 0; k < 64; ++k) wcol[k] = W[k * 64 + lane];
    for (int r = wave; r < TILE; r += NWAVES) {
        int d = t0 + r;
        if (d >= n) break;                       // wave-uniform
        const float4* ap = (const float4*)&sY[r * 64];
        float acc = 0.f;
#pragma unroll
        for (int k4 = 0; k4 < 16; ++k4) {
            float4 a4 = ap[k4];                  // uniform address -> broadcast b128
            acc = fmaf(a4.x, wcol[4 * k4 + 0], acc);
            acc = fmaf(a4.y, wcol[4 * k4 + 1], acc);
            acc = fmaf(a4.z, wcol[4 * k4 + 2], acc);
            acc = fmaf(a4.w, wcol[4 * k4 + 3], acc);
        }
        gOut[(size_t)d * 64 + lane] = __float2bfloat16(acc * sDD[r]);
    }
}

// Tiled last hidden conv fused with 64->1 matmul: zg[d] = (relu(dd*y+b) . Wout) * dd
__global__ __launch_bounds__(TPB_T) void k_gconv_z_t(
    const bf16* __restrict__ gIn, const float* __restrict__ dinv,
    const int* __restrict__ row_start, const unsigned* __restrict__ bucket,
    const float* __restrict__ bias, const float* __restrict__ Wout,
    float* __restrict__ zg, int n, int E) {
    __shared__ float sY[TILE * 64];
    __shared__ float sDD[TILE];
    int tid = threadIdx.x, wave = tid >> 6, lane = tid & 63;
    int t0 = blockIdx.x * TILE;
    for (int r = wave; r < TILE; r += NWAVES) {
        int d = t0 + r;
        float v = 0.f;
        if (d < n) v = B2F(gIn[(size_t)d * 64 + lane]);
        sY[r * 64 + lane] = v;
        if (lane == 0) sDD[r] = (d < n) ? dinv[d] : 0.f;
    }
    int e0 = row_start[t0];
    int e1 = row_start[min(t0 + TILE, n)];
    e0 = max(0, min(e0, E)); e1 = max(e0, min(e1, E));
    __syncthreads();
    tile_edges(sY, gIn, bucket, e0, e1, wave, lane, (unsigned)(n - 1), (unsigned)(E - 1));
    __syncthreads();
    float bj = bias[lane], wj = Wout[lane];
    for (int r = wave; r < TILE; r += NWAVES) {
        int d = t0 + r;
        if (d >= n) break;
        float v = fmaxf(fmaf(sDD[r], sY[r * 64 + lane], bj), 0.f) * wj;
#pragma unroll
        for (int off = 32; off > 0; off >>= 1) v += __shfl_down(v, off);
        if (lane == 0) zg[d] = v * sDD[r];
    }
}

// out[d] = dd*(zg[d] + sum zg[s]) + b_out.  One wave per node, lane = neighbor.
__global__ __launch_bounds__(TPB) void k_out(
    const float* __restrict__ zg, const float* __restrict__ dinv,
    const int* __restrict__ row_start, const unsigned* __restrict__ bucket,
    const float* __restrict__ b_out, float* __restrict__ out, int n, int E) {
    int t = blockIdx.x * blockDim.x + threadIdx.x;
    int d = t >> 6, lane = t & 63;
    if (d >= n) return;
    int k0 = row_start[d], k1 = row_start[d + 1];
    k1 = min(k1, E); k0 = max(min(k0, k1), 0);
    unsigned nm1 = (unsigned)(n - 1);
    float v = 0.f;
    for (int k = k0 + lane; k < k1; k += 64) {
        unsigned s = min(bucket[k] & 0xFFFFu, nm1);
        v += zg[s];
    }
#pragma unroll
    for (int off = 32; off > 0; off >>= 1) v += __shfl_down(v, off);
    if (lane == 0) out[d] = fmaf(zg[d] + v, dinv[d], b_out[0]);
}

extern "C" void kernel_launch(void* const* d_in, const int* in_sizes, int n_in,
                              void* d_out, int out_size, void* d_ws, size_t ws_size,
                              hipStream_t stream) {
    const float* x     = (const float*)d_in[0];
    const int*   ei    = (const int*)d_in[1];
    const float* W_in  = (const float*)d_in[2];
    const float* b_in  = (const float*)d_in[3];
    const float* W_h   = (const float*)d_in[4];
    const float* b_h   = (const float*)d_in[5];
    const float* W_out = (const float*)d_in[6];
    const float* b_out = (const float*)d_in[7];
    float* out = (float*)d_out;

    int N = in_sizes[0] / 4;
    int E = in_sizes[1] / 2;
    const int* src = ei;
    const int* dst = ei + E;

    char* ws = (char*)d_ws;
    bf16* gA           = (bf16*)ws;     ws += (size_t)N * 64 * 2;
    bf16* gB           = (bf16*)ws;     ws += (size_t)N * 64 * 2;
    unsigned* bucket   = (unsigned*)ws; ws += (size_t)E * 4;
    int*  row_start    = (int*)ws;      ws += (size_t)(N + 1) * 4;
    int*  cursor       = (int*)ws;      ws += (size_t)N * 4;
    int*  cnt          = (int*)ws;      ws += (size_t)N * 4;
    float* dinv        = (float*)ws;    ws += (size_t)N * 4;
    float* zg          = (float*)ws;    ws += (size_t)N * 4;
    int*  bsum         = (int*)ws;      // 257 ints

    int gN  = (N + TPB - 1) / TPB;       // scan chunk count (<=256 for N<=65536)
    int gE  = (E + TPB - 1) / TPB;
    int gNF = (N * 64 + TPB - 1) / TPB;
    int gN4 = (N + 3) / 4;               // 4 nodes/block (k_out)
    int gT  = (N + TILE - 1) / TILE;     // 1563 tiles

    // ---- CSR build + norms ----
    k_zero_cnt<<<gN, TPB, 0, stream>>>(cnt, N);
    k_hist<<<gE, TPB, 0, stream>>>(dst, cnt, E, N);
    k_blocksum<<<gN, TPB, 0, stream>>>(cnt, bsum, N);
    k_scan_bsum<<<1, TPB, 0, stream>>>(bsum, gN);
    k_scan_final<<<gN, TPB, 0, stream>>>(cnt, bsum, row_start, cursor, dinv, N);
    k_scatter<<<gE, TPB, 0, stream>>>(src, dst, cursor, bucket, E, N);

    // ---- layers (feature buffers premultiplied by dinv) ----
    k_mm_in<<<gNF, TPB, 0, stream>>>(x, W_in, dinv, gA, N);
    k_gconv_t<<<gT, TPB_T, 0, stream>>>(gA, dinv, row_start, bucket, b_in, W_h, gB, N, E);
    k_gconv_t<<<gT, TPB_T, 0, stream>>>(gB, dinv, row_start, bucket, b_h, W_h + 4096, gA, N, E);
    k_gconv_t<<<gT, TPB_T, 0, stream>>>(gA, dinv, row_start, bucket, b_h + 64, W_h + 8192, gB, N, E);
    k_gconv_z_t<<<gT, TPB_T, 0, stream>>>(gB, dinv, row_start, bucket, b_h + 128, W_out, zg, N, E);
    k_out<<<gN4, TPB, 0, stream>>>(zg, dinv, row_start, bucket, b_out, out, N, E);
}

// Round 10
// 316.840 us; speedup vs baseline: 5.1012x; 4.4992x over previous
//
#include <hip/hip_runtime.h>
#include <hip/hip_bf16.h>

// GCN: N=50000, E=800000, hidden 64, 5 convs (relu on first 4).
// f32 tensors, int32 edge_index, f32 d_out[N].  ws_size in [19.8, 26.0) MB.
// Round-9 post-mortem: LDS-tile edge-parallel gconv is ~6x worse per wave than the
// per-node gather at EQUAL wave count (319 us, occ 38%, VALU 4.8%) -> reverted to the
// round-7 per-node structure (351 us) and improved its gather instead:
//   QUAD GATHER: 4 edges per load instr — lane group g=lane>>4 takes edge k+g, lane
//   i=lane&15 loads uint2 = 4 packed bf16 feats (64 lanes x 8B = 4 full rows, coalesced).
//   Indices via __shfl (bpermute); butterfly (xor 16,32) combines group partials;
//   lanes 0-15 write the row to LDS; r7's transform+matmul unchanged.
// bucket is now ushort[src] (N < 65536) — also probes scatter write-amp model.
// Workspace (~15.4 MB): gA bf16[N*64] | gB bf16[N*64] | bucket u16[E] | row_start i32[N+1]
//                       | cursor i32[N] | cnt i32[N] | dinv f32[N] | zg f32[N] | bsum i32[257]

#define TPB 256
typedef __hip_bfloat16 bf16;
#define B2F __bfloat162float

__global__ void k_zero_cnt(int* __restrict__ cnt, int n) {
    int i = blockIdx.x * blockDim.x + threadIdx.x;
    if (i < n) cnt[i] = 0;
}

__global__ void k_hist(const int* __restrict__ dst, int* __restrict__ cnt, int E, int n) {
    int e = blockIdx.x * blockDim.x + threadIdx.x;
    if (e < E) {
        int d = dst[e];
        if ((unsigned)d < (unsigned)n) atomicAdd(&cnt[d], 1);
    }
}

__global__ void k_blocksum(const int* __restrict__ cnt, int* __restrict__ bsum, int n) {
    __shared__ int s[TPB];
    int i = blockIdx.x * TPB + threadIdx.x;
    s[threadIdx.x] = (i < n) ? cnt[i] : 0;
    __syncthreads();
    for (int off = TPB / 2; off > 0; off >>= 1) {
        if (threadIdx.x < off) s[threadIdx.x] += s[threadIdx.x + off];
        __syncthreads();
    }
    if (threadIdx.x == 0) bsum[blockIdx.x] = s[0];
}

__global__ void k_scan_bsum(int* __restrict__ bsum, int nb) {
    __shared__ int s[TPB];
    int t = threadIdx.x;
    int v = (t < nb) ? bsum[t] : 0;
    s[t] = v;
    __syncthreads();
    for (int off = 1; off < TPB; off <<= 1) {
        int u = (t >= off) ? s[t - off] : 0;
        __syncthreads();
        s[t] += u;
        __syncthreads();
    }
    if (t < nb) bsum[t] = s[t] - v;  // exclusive
}

__global__ void k_scan_final(const int* __restrict__ cnt, const int* __restrict__ bsum,
                             int* __restrict__ row_start, int* __restrict__ cursor,
                             float* __restrict__ dinv, int n) {
    __shared__ int s[TPB];
    int t = threadIdx.x;
    int i = blockIdx.x * TPB + t;
    int v = (i < n) ? cnt[i] : 0;
    s[t] = v;
    __syncthreads();
    for (int off = 1; off < TPB; off <<= 1) {
        int u = (t >= off) ? s[t - off] : 0;
        __syncthreads();
        s[t] += u;
        __syncthreads();
    }
    if (i < n) {
        int excl = bsum[blockIdx.x] + s[t] - v;
        row_start[i] = excl;
        cursor[i] = excl;
        dinv[i] = rsqrtf((float)v + 1.0f);   // +1 self-loop
        if (i == n - 1) row_start[n] = excl + v;
    }
}

__global__ void k_scatter(const int* __restrict__ src, const int* __restrict__ dst,
                          int* __restrict__ cursor, unsigned short* __restrict__ bucket,
                          int E, int n) {
    int e = blockIdx.x * blockDim.x + threadIdx.x;
    if (e < E) {
        int d = dst[e], s = src[e];
        if ((unsigned)d >= (unsigned)n || (unsigned)s >= (unsigned)n) return;
        int pos = atomicAdd(&cursor[d], 1);
        if ((unsigned)pos < (unsigned)E) bucket[pos] = (unsigned short)s;  // replay-safe
    }
}

// g1[i][j] = (sum_{k<4} x[i][k] * W_in[k][j]) * dinv[i]   (premultiplied)
__global__ void k_mm_in(const float* __restrict__ x, const float* __restrict__ W,
                        const float* __restrict__ dinv, bf16* __restrict__ g, int n) {
    int t = blockIdx.x * blockDim.x + threadIdx.x;
    if (t >= n * 64) return;
    int i = t >> 6, j = t & 63;
    float acc = 0.f;
#pragma unroll
    for (int k = 0; k < 4; ++k) acc = fmaf(x[i * 4 + k], W[k * 64 + j], acc);
    g[t] = __float2bfloat16(acc * dinv[i]);
}

__device__ __forceinline__ void acc_quad(float4& a, uint2 w) {
    a.x += __uint_as_float(w.x << 16);
    a.y += __uint_as_float(w.x & 0xffff0000u);
    a.z += __uint_as_float(w.y << 16);
    a.w += __uint_as_float(w.y & 0xffff0000u);
}

// Quad gather: per node, 4 edges per load instruction. After the butterfly every
// lane holds the full neighbor+self sum for its quad; lanes 0-15 write the row.
__device__ __forceinline__ void agg_row_quad(const bf16* __restrict__ g,
                                             const unsigned short* __restrict__ bucket,
                                             int k0, int k1, int d, float* __restrict__ sVrow,
                                             int lane, unsigned nm1, unsigned Em1) {
    int grp = lane >> 4, i = lane & 15;
    float4 a = {0.f, 0.f, 0.f, 0.f};
    // self term (only group 0 adds it)
    if (grp == 0) {
        uint2 w = *(const uint2*)(g + (size_t)d * 64 + 4 * i);
        acc_quad(a, w);
    }
    for (int base = k0; base < k1; base += 64) {
        int cnt = min(64, k1 - base);
        int rec = bucket[min((unsigned)(base + lane), Em1)];  // coalesced u16 load
        int k = 0;
        for (; k + 16 <= cnt; k += 16) {                      // 16 edges, 4 quad loads
            unsigned s0 = min((unsigned)__shfl(rec, k + 0 + grp), nm1);
            unsigned s1 = min((unsigned)__shfl(rec, k + 4 + grp), nm1);
            unsigned s2 = min((unsigned)__shfl(rec, k + 8 + grp), nm1);
            unsigned s3 = min((unsigned)__shfl(rec, k + 12 + grp), nm1);
            uint2 w0 = *(const uint2*)(g + (size_t)s0 * 64 + 4 * i);
            uint2 w1 = *(const uint2*)(g + (size_t)s1 * 64 + 4 * i);
            uint2 w2 = *(const uint2*)(g + (size_t)s2 * 64 + 4 * i);
            uint2 w3 = *(const uint2*)(g + (size_t)s3 * 64 + 4 * i);
            acc_quad(a, w0); acc_quad(a, w1); acc_quad(a, w2); acc_quad(a, w3);
        }
        for (; k < cnt; k += 4) {                             // tail, predicated
            int e = k + grp;
            unsigned s = min((unsigned)__shfl(rec, min(e, 63)), nm1);
            uint2 w = *(const uint2*)(g + (size_t)s * 64 + 4 * i);
            if (e < cnt) acc_quad(a, w);
        }
    }
    // combine the 4 lane-group partials: butterfly xor 16, 32
#pragma unroll
    for (int m = 16; m < 64; m <<= 1) {
        a.x += __shfl_xor(a.x, m);
        a.y += __shfl_xor(a.y, m);
        a.z += __shfl_xor(a.z, m);
        a.w += __shfl_xor(a.w, m);
    }
    if (grp == 0) ((float4*)sVrow)[i] = a;
}

// Fused layer: one wave per node (4 nodes/block). sum -> LDS row; a = relu(dd*sum+bias);
// gOut = (a @ W) * dd with W staged in LDS.
__global__ __launch_bounds__(TPB) void k_gconv(
    const bf16* __restrict__ gIn, const float* __restrict__ dinv,
    const int* __restrict__ row_start, const unsigned short* __restrict__ bucket,
    const float* __restrict__ bias, const float* __restrict__ W,
    bf16* __restrict__ gOut, int n, int E) {
    __shared__ float sW[64 * 64];
    __shared__ float sV[4][64];
    int tid = threadIdx.x;
    for (int k = tid; k < 1024; k += TPB) ((float4*)sW)[k] = ((const float4*)W)[k];
    int r = tid >> 6, j = tid & 63;
    int d = blockIdx.x * 4 + r;
    float dd = 0.f;
    if (d < n) {                                   // wave-uniform branch
        dd = dinv[d];
        int k0 = row_start[d], k1 = row_start[d + 1];
        k1 = min(k1, E); k0 = max(min(k0, k1), 0);
        agg_row_quad(gIn, bucket, k0, k1, d, sV[r], j, (unsigned)(n - 1), (unsigned)(E - 1));
    }
    __syncthreads();
    // transform in LDS: a = relu(dd*sum + bias)
    if (d < n) sV[r][j] = fmaxf(fmaf(dd, sV[r][j], bias[j]), 0.f);
    __syncthreads();
    if (d >= n) return;
    float acc = 0.f;
#pragma unroll
    for (int k = 0; k < 64; ++k) acc = fmaf(sV[r][k], sW[k * 64 + j], acc);
    gOut[(size_t)d * 64 + j] = __float2bfloat16(acc * dd);
}

// Last hidden conv fused with 64->1 matmul: zg[d] = (relu(dd*sum+b) . Wout) * dd
__global__ __launch_bounds__(TPB) void k_gconv_z(
    const bf16* __restrict__ gIn, const float* __restrict__ dinv,
    const int* __restrict__ row_start, const unsigned short* __restrict__ bucket,
    const float* __restrict__ bias, const float* __restrict__ Wout,
    float* __restrict__ zg, int n, int E) {
    __shared__ float sV[4][64];
    int tid = threadIdx.x;
    int r = tid >> 6, j = tid & 63;
    int d = blockIdx.x * 4 + r;
    if (d >= n) return;                            // wave-uniform
    float dd = dinv[d];
    int k0 = row_start[d], k1 = row_start[d + 1];
    k1 = min(k1, E); k0 = max(min(k0, k1), 0);
    agg_row_quad(gIn, bucket, k0, k1, d, sV[r], j, (unsigned)(n - 1), (unsigned)(E - 1));
    __syncthreads();
    float v = fmaxf(fmaf(dd, sV[r][j], bias[j]), 0.f) * Wout[j];
#pragma unroll
    for (int off = 32; off > 0; off >>= 1) v += __shfl_down(v, off);
    if (j == 0) zg[d] = v * dd;
}

// out[d] = dd*(zg[d] + sum zg[s]) + b_out.  One wave per node, lane = neighbor.
__global__ __launch_bounds__(TPB) void k_out(
    const float* __restrict__ zg, const float* __restrict__ dinv,
    const int* __restrict__ row_start, const unsigned short* __restrict__ bucket,
    const float* __restrict__ b_out, float* __restrict__ out, int n, int E) {
    int t = blockIdx.x * blockDim.x + threadIdx.x;
    int d = t >> 6, lane = t & 63;
    if (d >= n) return;
    int k0 = row_start[d], k1 = row_start[d + 1];
    k1 = min(k1, E); k0 = max(min(k0, k1), 0);
    unsigned nm1 = (unsigned)(n - 1);
    float v = 0.f;
    for (int k = k0 + lane; k < k1; k += 64) {
        unsigned s = min((unsigned)bucket[k], nm1);
        v += zg[s];
    }
#pragma unroll
    for (int off = 32; off > 0; off >>= 1) v += __shfl_down(v, off);
    if (lane == 0) out[d] = fmaf(zg[d] + v, dinv[d], b_out[0]);
}

extern "C" void kernel_launch(void* const* d_in, const int* in_sizes, int n_in,
                              void* d_out, int out_size, void* d_ws, size_t ws_size,
                              hipStream_t stream) {
    const float* x     = (const float*)d_in[0];
    const int*   ei    = (const int*)d_in[1];
    const float* W_in  = (const float*)d_in[2];
    const float* b_in  = (const float*)d_in[3];
    const float* W_h   = (const float*)d_in[4];
    const float* b_h   = (const float*)d_in[5];
    const float* W_out = (const float*)d_in[6];
    const float* b_out = (const float*)d_in[7];
    float* out = (float*)d_out;

    int N = in_sizes[0] / 4;
    int E = in_sizes[1] / 2;
    const int* src = ei;
    const int* dst = ei + E;

    char* ws = (char*)d_ws;
    bf16* gA              = (bf16*)ws;           ws += (size_t)N * 64 * 2;
    bf16* gB              = (bf16*)ws;           ws += (size_t)N * 64 * 2;
    unsigned short* bucket = (unsigned short*)ws; ws += (size_t)E * 2;
    int*  row_start       = (int*)ws;            ws += (size_t)(N + 1) * 4;
    int*  cursor          = (int*)ws;            ws += (size_t)N * 4;
    int*  cnt             = (int*)ws;            ws += (size_t)N * 4;
    float* dinv           = (float*)ws;          ws += (size_t)N * 4;
    float* zg             = (float*)ws;          ws += (size_t)N * 4;
    int*  bsum            = (int*)ws;            // 257 ints

    int gN  = (N + TPB - 1) / TPB;       // scan chunk count (<=256 for N<=65536)
    int gE  = (E + TPB - 1) / TPB;
    int gNF = (N * 64 + TPB - 1) / TPB;
    int gN4 = (N + 3) / 4;               // 4 nodes/block (1 wave per node)

    // ---- CSR build + norms ----
    k_zero_cnt<<<gN, TPB, 0, stream>>>(cnt, N);
    k_hist<<<gE, TPB, 0, stream>>>(dst, cnt, E, N);
    k_blocksum<<<gN, TPB, 0, stream>>>(cnt, bsum, N);
    k_scan_bsum<<<1, TPB, 0, stream>>>(bsum, gN);
    k_scan_final<<<gN, TPB, 0, stream>>>(cnt, bsum, row_start, cursor, dinv, N);
    k_scatter<<<gE, TPB, 0, stream>>>(src, dst, cursor, bucket, E, N);

    // ---- layers (feature buffers premultiplied by dinv) ----
    k_mm_in<<<gNF, TPB, 0, stream>>>(x, W_in, dinv, gA, N);
    k_gconv<<<gN4, TPB, 0, stream>>>(gA, dinv, row_start, bucket, b_in, W_h, gB, N, E);
    k_gconv<<<gN4, TPB, 0, stream>>>(gB, dinv, row_start, bucket, b_h, W_h + 4096, gA, N, E);
    k_gconv<<<gN4, TPB, 0, stream>>>(gA, dinv, row_start, bucket, b_h + 64, W_h + 8192, gB, N, E);
    k_gconv_z<<<gN4, TPB, 0, stream>>>(gB, dinv, row_start, bucket, b_h + 128, W_out, zg, N, E);
    k_out<<<gN4, TPB, 0, stream>>>(zg, dinv, row_start, bucket, b_out, out, N, E);
}

// Round 11
// 310.492 us; speedup vs baseline: 5.2055x; 1.0204x over previous
//
#include <hip/hip_runtime.h>
#include <hip/hip_bf16.h>

// GCN: N=50000, E=800000, hidden 64, 5 convs (relu on first 4).
// f32 tensors, int32 edge_index, f32 d_out[N].  ws_size in [19.8, 26.0) MB.
// Round-10: 317 us; k_scatter #1 (~50 us, WRITE 42 MB = per-LINE amplification of
// random 2B stores). This round:
//  (1) two-pass binned scatter: k_bin (LDS histogram over dst>>8 buckets, per-bucket
//      range reservation, ~contiguous run writes into staging) + k_unbin (one block
//      per bucket, scatter within an ~8KB L2-resident region) -> ~10 MB writes total.
//  (2) gconv: butterfly (8 chained bpermutes) replaced by per-group LDS partial rows
//      summed in the transform step (4 conflict-free ds_read_b32).
// Workspace (~18.6 MB): gA bf16[N*64] | gB bf16[N*64] | bucket u16[E] | staging u32[E]
//   | row_start i32[N+1] | cursor i32[N] | cnt i32[N] | dinv f32[N] | zg f32[N]
//   | bsum i32[257] | bcur i32[256]

#define TPB 256
#define EPT 8                    // edges per thread in k_bin
#define CHUNK (TPB * EPT)        // 2048 edges per block
typedef __hip_bfloat16 bf16;
#define B2F __bfloat162float

__global__ void k_zero_cnt(int* __restrict__ cnt, int n) {
    int i = blockIdx.x * blockDim.x + threadIdx.x;
    if (i < n) cnt[i] = 0;
}

__global__ void k_hist(const int* __restrict__ dst, int* __restrict__ cnt, int E, int n) {
    int e = blockIdx.x * blockDim.x + threadIdx.x;
    if (e < E) {
        int d = dst[e];
        if ((unsigned)d < (unsigned)n) atomicAdd(&cnt[d], 1);
    }
}

__global__ void k_blocksum(const int* __restrict__ cnt, int* __restrict__ bsum, int n) {
    __shared__ int s[TPB];
    int i = blockIdx.x * TPB + threadIdx.x;
    s[threadIdx.x] = (i < n) ? cnt[i] : 0;
    __syncthreads();
    for (int off = TPB / 2; off > 0; off >>= 1) {
        if (threadIdx.x < off) s[threadIdx.x] += s[threadIdx.x + off];
        __syncthreads();
    }
    if (threadIdx.x == 0) bsum[blockIdx.x] = s[0];
}

__global__ void k_scan_bsum(int* __restrict__ bsum, int nb) {
    __shared__ int s[TPB];
    int t = threadIdx.x;
    int v = (t < nb) ? bsum[t] : 0;
    s[t] = v;
    __syncthreads();
    for (int off = 1; off < TPB; off <<= 1) {
        int u = (t >= off) ? s[t - off] : 0;
        __syncthreads();
        s[t] += u;
        __syncthreads();
    }
    if (t < nb) bsum[t] = s[t] - v;  // exclusive
}

__global__ void k_scan_final(const int* __restrict__ cnt, const int* __restrict__ bsum,
                             int* __restrict__ row_start, int* __restrict__ cursor,
                             float* __restrict__ dinv, int n) {
    __shared__ int s[TPB];
    int t = threadIdx.x;
    int i = blockIdx.x * TPB + t;
    int v = (i < n) ? cnt[i] : 0;
    s[t] = v;
    __syncthreads();
    for (int off = 1; off < TPB; off <<= 1) {
        int u = (t >= off) ? s[t - off] : 0;
        __syncthreads();
        s[t] += u;
        __syncthreads();
    }
    if (i < n) {
        int excl = bsum[blockIdx.x] + s[t] - v;
        row_start[i] = excl;
        cursor[i] = excl;
        dinv[i] = rsqrtf((float)v + 1.0f);   // +1 self-loop
        if (i == n - 1) row_start[n] = excl + v;
    }
}

// bcur[b] = CSR start of dst-bucket b (bucket = dst >> 8)
__global__ void k_init_bcur(const int* __restrict__ row_start, int* __restrict__ bcur,
                            int B, int n) {
    int b = threadIdx.x;
    if (b < B) bcur[b] = row_start[min(b << 8, n)];
}

// Pass 1: bin edges by dst>>8 into staging (record = src | (dst&255)<<16).
// Per-block LDS histogram -> one global atomic per touched bucket -> run writes.
__global__ __launch_bounds__(TPB) void k_bin(
    const int* __restrict__ src, const int* __restrict__ dst,
    int* __restrict__ bcur, unsigned* __restrict__ staging, int E, int n) {
    __shared__ int hcnt[256];
    __shared__ int hbase[256];
    int tid = threadIdx.x;
    int e0 = blockIdx.x * CHUNK;
    hcnt[tid] = 0;
    __syncthreads();

    int eb[EPT];        // bucket id or -1
    unsigned rec[EPT];  // packed record
#pragma unroll
    for (int u = 0; u < EPT; ++u) {
        int e = e0 + u * TPB + tid;
        eb[u] = -1;
        if (e < E) {
            int d = dst[e], s = src[e];
            if ((unsigned)d < (unsigned)n && (unsigned)s < (unsigned)n) {
                eb[u] = d >> 8;
                rec[u] = (unsigned)s | ((unsigned)(d & 255) << 16);
                atomicAdd(&hcnt[eb[u]], 1);
            }
        }
    }
    __syncthreads();
    int c = hcnt[tid];
    hbase[tid] = (c > 0) ? atomicAdd(&bcur[tid], c) : 0;
    hcnt[tid] = 0;
    __syncthreads();
#pragma unroll
    for (int u = 0; u < EPT; ++u) {
        if (eb[u] >= 0) {
            int r = atomicAdd(&hcnt[eb[u]], 1);
            int pos = hbase[eb[u]] + r;
            if ((unsigned)pos < (unsigned)E) staging[pos] = rec[u];  // replay-safe
        }
    }
}

// Pass 2: one block per bucket; scatter staged records into the final u16 CSR
// region (small, L2-resident -> no line amplification to HBM).
__global__ __launch_bounds__(TPB) void k_unbin(
    const unsigned* __restrict__ staging, const int* __restrict__ row_start,
    int* __restrict__ cursor, unsigned short* __restrict__ bucket, int E, int n) {
    int b = blockIdx.x;
    int lo = row_start[min(b << 8, n)];
    int hi = row_start[min((b + 1) << 8, n)];
    lo = max(0, min(lo, E)); hi = max(lo, min(hi, E));
    for (int i = lo + threadIdx.x; i < hi; i += TPB) {
        unsigned r = staging[i];
        int d = min((b << 8) + (int)(r >> 16), n - 1);
        int pos = atomicAdd(&cursor[d], 1);
        if ((unsigned)pos < (unsigned)E) bucket[pos] = (unsigned short)(r & 0xffffu);
    }
}

// g1[i][j] = (sum_{k<4} x[i][k] * W_in[k][j]) * dinv[i]   (premultiplied)
__global__ void k_mm_in(const float* __restrict__ x, const float* __restrict__ W,
                        const float* __restrict__ dinv, bf16* __restrict__ g, int n) {
    int t = blockIdx.x * blockDim.x + threadIdx.x;
    if (t >= n * 64) return;
    int i = t >> 6, j = t & 63;
    float acc = 0.f;
#pragma unroll
    for (int k = 0; k < 4; ++k) acc = fmaf(x[i * 4 + k], W[k * 64 + j], acc);
    g[t] = __float2bfloat16(acc * dinv[i]);
}

__device__ __forceinline__ void acc_quad(float4& a, uint2 w) {
    a.x += __uint_as_float(w.x << 16);
    a.y += __uint_as_float(w.x & 0xffff0000u);
    a.z += __uint_as_float(w.y << 16);
    a.w += __uint_as_float(w.y & 0xffff0000u);
}

// Quad gather: 4 edges per load instruction; lane group g=lane>>4 takes edge k+g,
// lane i=lane&15 loads uint2 = 4 packed bf16 feats. Each group writes its float4
// partial to its own LDS row (no butterfly); transform sums the 4 rows.
__device__ __forceinline__ void agg_row_quad(const bf16* __restrict__ g,
                                             const unsigned short* __restrict__ bucket,
                                             int k0, int k1, int d, float* __restrict__ sVp,
                                             int lane, unsigned nm1, unsigned Em1) {
    int grp = lane >> 4, i = lane & 15;
    float4 a = {0.f, 0.f, 0.f, 0.f};
    if (grp == 0) {  // self term
        uint2 w = *(const uint2*)(g + (size_t)d * 64 + 4 * i);
        acc_quad(a, w);
    }
    for (int base = k0; base < k1; base += 64) {
        int cnt = min(64, k1 - base);
        int rec = bucket[min((unsigned)(base + lane), Em1)];  // coalesced u16 load
        int k = 0;
        for (; k + 16 <= cnt; k += 16) {                      // 16 edges, 4 quad loads
            unsigned s0 = min((unsigned)__shfl(rec, k + 0 + grp), nm1);
            unsigned s1 = min((unsigned)__shfl(rec, k + 4 + grp), nm1);
            unsigned s2 = min((unsigned)__shfl(rec, k + 8 + grp), nm1);
            unsigned s3 = min((unsigned)__shfl(rec, k + 12 + grp), nm1);
            uint2 w0 = *(const uint2*)(g + (size_t)s0 * 64 + 4 * i);
            uint2 w1 = *(const uint2*)(g + (size_t)s1 * 64 + 4 * i);
            uint2 w2 = *(const uint2*)(g + (size_t)s2 * 64 + 4 * i);
            uint2 w3 = *(const uint2*)(g + (size_t)s3 * 64 + 4 * i);
            acc_quad(a, w0); acc_quad(a, w1); acc_quad(a, w2); acc_quad(a, w3);
        }
        for (; k < cnt; k += 4) {                             // tail, predicated
            int e = k + grp;
            unsigned s = min((unsigned)__shfl(rec, min(e, 63)), nm1);
            uint2 w = *(const uint2*)(g + (size_t)s * 64 + 4 * i);
            if (e < cnt) acc_quad(a, w);
        }
    }
    ((float4*)(sVp + grp * 64))[i] = a;   // partial row per group
}

// Fused layer: one wave per node (4 nodes/block). Partials -> LDS; transform sums 4
// rows, applies relu(dd*sum+bias); matmul with W staged in LDS; gOut = (a@W)*dd.
__global__ __launch_bounds__(TPB) void k_gconv(
    const bf16* __restrict__ gIn, const float* __restrict__ dinv,
    const int* __restrict__ row_start, const unsigned short* __restrict__ bucket,
    const float* __restrict__ bias, const float* __restrict__ W,
    bf16* __restrict__ gOut, int n, int E) {
    __shared__ float sW[64 * 64];
    __shared__ float sVp[4][4 * 64];     // [node-in-block][group][64]
    int tid = threadIdx.x;
    for (int k = tid; k < 1024; k += TPB) ((float4*)sW)[k] = ((const float4*)W)[k];
    int r = tid >> 6, j = tid & 63;
    int d = blockIdx.x * 4 + r;
    float dd = 0.f;
    if (d < n) {                                   // wave-uniform branch
        dd = dinv[d];
        int k0 = row_start[d], k1 = row_start[d + 1];
        k1 = min(k1, E); k0 = max(min(k0, k1), 0);
        agg_row_quad(gIn, bucket, k0, k1, d, sVp[r], j, (unsigned)(n - 1), (unsigned)(E - 1));
    }
    __syncthreads();
    // transform: sum 4 group partials, a = relu(dd*sum + bias)
    float v = sVp[r][j] + sVp[r][64 + j] + sVp[r][128 + j] + sVp[r][192 + j];
    float a = fmaxf(fmaf(dd, v, bias[j]), 0.f);
    if (d < n) sVp[r][j] = a;                      // row 0 holds the activation
    __syncthreads();
    if (d >= n) return;
    const float4* ap = (const float4*)&sVp[r][0];
    float acc = 0.f;
#pragma unroll
    for (int k4 = 0; k4 < 16; ++k4) {
        float4 a4 = ap[k4];
        acc = fmaf(a4.x, sW[(4 * k4 + 0) * 64 + j], acc);
        acc = fmaf(a4.y, sW[(4 * k4 + 1) * 64 + j], acc);
        acc = fmaf(a4.z, sW[(4 * k4 + 2) * 64 + j], acc);
        acc = fmaf(a4.w, sW[(4 * k4 + 3) * 64 + j], acc);
    }
    gOut[(size_t)d * 64 + j] = __float2bfloat16(acc * dd);
}

// Last hidden conv fused with 64->1 matmul: zg[d] = (relu(dd*sum+b) . Wout) * dd
__global__ __launch_bounds__(TPB) void k_gconv_z(
    const bf16* __restrict__ gIn, const float* __restrict__ dinv,
    const int* __restrict__ row_start, const unsigned short* __restrict__ bucket,
    const float* __restrict__ bias, const float* __restrict__ Wout,
    float* __restrict__ zg, int n, int E) {
    __shared__ float sVp[4][4 * 64];
    int tid = threadIdx.x;
    int r = tid >> 6, j = tid & 63;
    int d = blockIdx.x * 4 + r;
    float dd = 0.f;
    if (d < n) {
        dd = dinv[d];
        int k0 = row_start[d], k1 = row_start[d + 1];
        k1 = min(k1, E); k0 = max(min(k0, k1), 0);
        agg_row_quad(gIn, bucket, k0, k1, d, sVp[r], j, (unsigned)(n - 1), (unsigned)(E - 1));
    }
    __syncthreads();
    if (d >= n) return;
    float v = sVp[r][j] + sVp[r][64 + j] + sVp[r][128 + j] + sVp[r][192 + j];
    float a = fmaxf(fmaf(dd, v, bias[j]), 0.f) * Wout[j];
#pragma unroll
    for (int off = 32; off > 0; off >>= 1) a += __shfl_down(a, off);
    if (j == 0) zg[d] = a * dd;
}

// out[d] = dd*(zg[d] + sum zg[s]) + b_out.  One wave per node, lane = neighbor.
__global__ __launch_bounds__(TPB) void k_out(
    const float* __restrict__ zg, const float* __restrict__ dinv,
    const int* __restrict__ row_start, const unsigned short* __restrict__ bucket,
    const float* __restrict__ b_out, float* __restrict__ out, int n, int E) {
    int t = blockIdx.x * blockDim.x + threadIdx.x;
    int d = t >> 6, lane = t & 63;
    if (d >= n) return;
    int k0 = row_start[d], k1 = row_start[d + 1];
    k1 = min(k1, E); k0 = max(min(k0, k1), 0);
    unsigned nm1 = (unsigned)(n - 1);
    float v = 0.f;
    for (int k = k0 + lane; k < k1; k += 64) {
        unsigned s = min((unsigned)bucket[k], nm1);
        v += zg[s];
    }
#pragma unroll
    for (int off = 32; off > 0; off >>= 1) v += __shfl_down(v, off);
    if (lane == 0) out[d] = fmaf(zg[d] + v, dinv[d], b_out[0]);
}

extern "C" void kernel_launch(void* const* d_in, const int* in_sizes, int n_in,
                              void* d_out, int out_size, void* d_ws, size_t ws_size,
                              hipStream_t stream) {
    const float* x     = (const float*)d_in[0];
    const int*   ei    = (const int*)d_in[1];
    const float* W_in  = (const float*)d_in[2];
    const float* b_in  = (const float*)d_in[3];
    const float* W_h   = (const float*)d_in[4];
    const float* b_h   = (const float*)d_in[5];
    const float* W_out = (const float*)d_in[6];
    const float* b_out = (const float*)d_in[7];
    float* out = (float*)d_out;

    int N = in_sizes[0] / 4;
    int E = in_sizes[1] / 2;
    const int* src = ei;
    const int* dst = ei + E;

    char* ws = (char*)d_ws;
    bf16* gA               = (bf16*)ws;           ws += (size_t)N * 64 * 2;
    bf16* gB               = (bf16*)ws;           ws += (size_t)N * 64 * 2;
    unsigned short* bucket = (unsigned short*)ws; ws += (size_t)E * 2;
    unsigned* staging      = (unsigned*)ws;       ws += (size_t)E * 4;
    int*  row_start        = (int*)ws;            ws += (size_t)(N + 1) * 4;
    int*  cursor           = (int*)ws;            ws += (size_t)N * 4;
    int*  cnt              = (int*)ws;            ws += (size_t)N * 4;
    float* dinv            = (float*)ws;          ws += (size_t)N * 4;
    float* zg              = (float*)ws;          ws += (size_t)N * 4;
    int*  bsum             = (int*)ws;            ws += 257 * 4;
    int*  bcur             = (int*)ws;            // 256 ints

    int B   = (N + 255) >> 8;            // dst buckets (196 for N=50000; <=256)
    int gN  = (N + TPB - 1) / TPB;       // scan chunk count (<=256 for N<=65536)
    int gE  = (E + TPB - 1) / TPB;
    int gNF = (N * 64 + TPB - 1) / TPB;
    int gN4 = (N + 3) / 4;               // 4 nodes/block (1 wave per node)
    int gBin = (E + CHUNK - 1) / CHUNK;  // 391

    // ---- CSR build + norms ----
    k_zero_cnt<<<gN, TPB, 0, stream>>>(cnt, N);
    k_hist<<<gE, TPB, 0, stream>>>(dst, cnt, E, N);
    k_blocksum<<<gN, TPB, 0, stream>>>(cnt, bsum, N);
    k_scan_bsum<<<1, TPB, 0, stream>>>(bsum, gN);
    k_scan_final<<<gN, TPB, 0, stream>>>(cnt, bsum, row_start, cursor, dinv, N);
    k_init_bcur<<<1, TPB, 0, stream>>>(row_start, bcur, B, N);
    k_bin<<<gBin, TPB, 0, stream>>>(src, dst, bcur, staging, E, N);
    k_unbin<<<B, TPB, 0, stream>>>(staging, row_start, cursor, bucket, E, N);

    // ---- layers (feature buffers premultiplied by dinv) ----
    k_mm_in<<<gNF, TPB, 0, stream>>>(x, W_in, dinv, gA, N);
    k_gconv<<<gN4, TPB, 0, stream>>>(gA, dinv, row_start, bucket, b_in, W_h, gB, N, E);
    k_gconv<<<gN4, TPB, 0, stream>>>(gB, dinv, row_start, bucket, b_h, W_h + 4096, gA, N, E);
    k_gconv<<<gN4, TPB, 0, stream>>>(gA, dinv, row_start, bucket, b_h + 64, W_h + 8192, gB, N, E);
    k_gconv_z<<<gN4, TPB, 0, stream>>>(gB, dinv, row_start, bucket, b_h + 128, W_out, zg, N, E);
    k_out<<<gN4, TPB, 0, stream>>>(zg, dinv, row_start, bucket, b_out, out, N, E);
}